// Round 12
// baseline (37.895 us; speedup 1.0000x reference)
//
#include <hip/hip_runtime.h>

// Problem constants (B,S,D,M) = (8, 2048, 1024, 128), R = 257
#define SS 2048
#define DDIM 1024
#define D4 256          // DDIM / 4 (float4 columns)
#define BB 8
#define STRIP 8
#define NSTRIP (SS / STRIP)   // 256

typedef float f32x4 __attribute__((ext_vector_type(4)));

__device__ __forceinline__ float4 f4zero() { return make_float4(0.f, 0.f, 0.f, 0.f); }
__device__ __forceinline__ float4 f4add(float4 a, float4 b) {
    return make_float4(a.x + b.x, a.y + b.y, a.z + b.z, a.w + b.w);
}
__device__ __forceinline__ float4 f4sub(float4 a, float4 b) {
    return make_float4(a.x - b.x, a.y - b.y, a.z - b.z, a.w - b.w);
}
__device__ __forceinline__ float4 f4mul(float4 a, float4 b) {
    return make_float4(a.x * b.x, a.y * b.y, a.z * b.z, a.w * b.w);
}
__device__ __forceinline__ float4 f4fma(float4 a, float4 b, float4 c) {
    return make_float4(fmaf(a.x, b.x, c.x), fmaf(a.y, b.y, c.y),
                       fmaf(a.z, b.z, c.z), fmaf(a.w, b.w, c.w));
}
__device__ __forceinline__ float4 f4fmas(float s, float4 b, float4 c) {
    return make_float4(fmaf(s, b.x, c.x), fmaf(s, b.y, c.y),
                       fmaf(s, b.z, c.z), fmaf(s, b.w, c.w));
}
__device__ __forceinline__ float4 f4scale(float4 a, float s) {
    return make_float4(a.x * s, a.y * s, a.z * s, a.w * s);
}
__device__ __forceinline__ float4 f4adds(float4 a, float s) {
    return make_float4(a.x + s, a.y + s, a.z + s, a.w + s);
}
__device__ __forceinline__ void nt_store(float4* p, float4 v) {
    __builtin_nontemporal_store(*(f32x4*)&v, (f32x4*)p);   // out never re-read
}
__device__ __forceinline__ float4 nt_load(const float4* p) {
    f32x4 v = __builtin_nontemporal_load((const f32x4*)p); // x: streaming, L3 covers halo
    return *(float4*)&v;
}

// ---------------------------------------------------------------------------
// k_pre_lds: ONE setup kernel. Pre[r][d] = sum_{r'=1..r} table[r'][d].
// 64 blocks x 256 threads; 4-row register chunks + 6-step Hillis-Steele LDS
// scan; max dependent-load chain = 4 (deep chains in setup cost 7-14 us:
// r5/r7 lessons).
// ---------------------------------------------------------------------------
__global__ __launch_bounds__(256) void k_pre_lds(const float4* __restrict__ tbl4,
                                                 float4* __restrict__ pre) {
    __shared__ float4 buf[2][64][4];    // 8 KB ping-pong
    const int t = threadIdx.x;
    const int k = t >> 2;               // chunk 0..63
    const int j = t & 3;                // col-within-block
    const int col = (blockIdx.x << 2) + j;   // 0..255

    const float4 p1 = tbl4[(4 * k + 1) * D4 + col];
    const float4 p2 = f4add(p1, tbl4[(4 * k + 2) * D4 + col]);
    const float4 p3 = f4add(p2, tbl4[(4 * k + 3) * D4 + col]);
    const float4 p4 = f4add(p3, tbl4[(4 * k + 4) * D4 + col]);

    buf[0][k][j] = p4;
    __syncthreads();
    int pb = 0;
#pragma unroll
    for (int s = 1; s < 64; s <<= 1) {
        float4 v = buf[pb][k][j];
        if (k >= s) v = f4add(v, buf[pb][k - s][j]);
        buf[pb ^ 1][k][j] = v;
        pb ^= 1;
        __syncthreads();
    }
    const float4 base = f4sub(buf[pb][k][j], p4);   // exclusive: rows 1..4k

    if (k == 0) pre[col] = f4zero();                 // Pre[0] = 0
    pre[(4 * k + 1) * D4 + col] = f4add(base, p1);
    pre[(4 * k + 2) * D4 + col] = f4add(base, p2);
    pre[(4 * k + 3) * D4 + col] = f4add(base, p3);
    if (k < 63) pre[(4 * k + 4) * D4 + col] = f4add(base, p4);  // row 256 unused
}

// ---------------------------------------------------------------------------
// k_main: out[b,i,d] = (w0*x[b,i-1] + (w1+S-1)*x[b,i] + w2*x[b,i+1] + pos(i,d)) / S
// Interior i in [128,1919]: pos = K0 + i*(T[2M]-T[0]), fully hoisted.
// Proven config: STRIP=8, plain __launch_bounds__(256) (no min-waves arg:
// r9 spill disaster), NT stores (r11: big win — L2 churn was the limiter).
// THIS ROUND: NT loads on x too — reuse window is L3-covered (r9: FETCH==x
// size at 25% nominal halo), so free L2 from the read stream as well.
// ---------------------------------------------------------------------------
__global__ __launch_bounds__(256) void k_main(const float4* __restrict__ x4,
                                              const float4* __restrict__ tbl4,
                                              const float* __restrict__ w,
                                              const float4* __restrict__ bias4,
                                              const float4* __restrict__ pre4,
                                              float4* __restrict__ out4) {
    const int tid = threadIdx.x;          // d4
    const int bid = blockIdx.x;           // b*NSTRIP + strip
    const int strip = bid & (NSTRIP - 1);
    const int b = bid >> 8;               // log2(256)
    const int i0 = strip * STRIP;

    // hoisted per-d constants (regular loads: keep these L2-resident)
    const float4 T0  = tbl4[0 * D4 + tid];
    const float4 T2M = tbl4[256 * D4 + tid];
    const float4 Tm  = tbl4[128 * D4 + tid];
    const float4 Tmm = tbl4[127 * D4 + tid];
    const float4 Tmp = tbl4[129 * D4 + tid];
    const float4 bs  = bias4[tid];

    // w is (D,3) row-major; 3 float4s cover w for our 4 d's -> unscramble
    const float4* w4 = (const float4*)w;
    const float4 q0 = w4[3 * tid + 0];
    const float4 q1 = w4[3 * tid + 1];
    const float4 q2 = w4[3 * tid + 2];
    const float4 w0 = make_float4(q0.x, q0.w, q1.z, q2.y);
    const float4 w1 = make_float4(q0.y, q1.x, q1.w, q2.z);
    const float4 w2 = make_float4(q0.z, q1.y, q2.x, q2.w);
    const float4 w1s = f4adds(w1, (float)(SS - 1));
    const float invS = 1.0f / (float)SS;

    const float4* xr = x4 + (b * SS + i0) * D4 + tid;
    float4* orow = out4 + (b * SS + i0) * D4 + tid;

    if (strip >= 16 && strip <= 239) {
        // ------- interior path: i in [128, 1919] -------
        const float4 PF = pre4[255 * D4 + tid];
        float4 K0 = bs;
        K0 = f4fma(f4adds(w1, -1.f), Tm, K0);
        K0 = f4fma(w0, Tmm, K0);
        K0 = f4fma(w2, Tmp, K0);
        K0 = f4fmas(1920.f, T0, K0);
        K0 = f4fmas(-127.f, T2M, K0);
        K0 = f4add(K0, PF);
        const float4 Kc = f4sub(T2M, T0);
        // table constants dead from here -> small live set in the hot loop

        float4 xm = nt_load(&xr[-D4]);   // i0-1 >= 127: safe
        float4 x0 = nt_load(&xr[0]);
#pragma unroll
        for (int j = 0; j < STRIP; ++j) {
            const float4 xp = nt_load(&xr[(j + 1) * D4]);  // i0+STRIP <= 1920
            const float fi = (float)(i0 + j);
            float4 acc = f4fmas(fi, Kc, K0);
            acc = f4fma(w0, xm, acc);
            acc = f4fma(w1s, x0, acc);
            acc = f4fma(w2, xp, acc);
            nt_store(&orow[j * D4], f4scale(acc, invS));
            xm = x0; x0 = xp;
        }
    } else {
        // ------- edge path: general formula, per-i Pre lookups (L2-hot) -------
        float4 K0e = bs;
        K0e = f4fma(f4adds(w1, -1.f), Tm, K0e);
        const float4 w0Tmm = f4mul(w0, Tmm);
        const float4 w2Tmp = f4mul(w2, Tmp);

        float4 xm = (i0 == 0) ? f4zero() : nt_load(&xr[-D4]);
        float4 x0 = nt_load(&xr[0]);
#pragma unroll
        for (int j = 0; j < STRIP; ++j) {
            const int i = i0 + j;
            const float4 xp = (i < SS - 1) ? nt_load(&xr[(j + 1) * D4]) : f4zero();
            const int cl = max(0, 1920 - i);          // clipped -M count (T[0])
            const int ch = max(0, i - 127);           // clipped +M count (T[2M])
            const int hi = min(i + 128, 255);
            const int lom1 = max(i - 1920, 0);        // lo - 1
            const float4 ph = pre4[hi * D4 + tid];
            const float4 pl = pre4[lom1 * D4 + tid];
            float4 pos = f4add(K0e, f4sub(ph, pl));
            pos = f4fmas((float)cl, T0, pos);
            pos = f4fmas((float)ch, T2M, pos);
            if (i >= 1)      pos = f4add(pos, w0Tmm);
            if (i <= SS - 2) pos = f4add(pos, w2Tmp);
            float4 acc = f4fma(w0, xm, pos);
            acc = f4fma(w1s, x0, acc);
            acc = f4fma(w2, xp, acc);
            nt_store(&orow[j * D4], f4scale(acc, invS));
            xm = x0; x0 = xp;
        }
    }
}

extern "C" void kernel_launch(void* const* d_in, const int* in_sizes, int n_in,
                              void* d_out, int out_size, void* d_ws, size_t ws_size,
                              hipStream_t stream) {
    const float* x     = (const float*)d_in[0];   // (B,S,D)
    const float* table = (const float*)d_in[1];   // (R,D) = (257,1024)
    const float* w     = (const float*)d_in[2];   // (D,3)
    const float* bias  = (const float*)d_in[3];   // (D,)
    float* out = (float*)d_out;

    // ws layout: Pre[256][1024] floats (1 MiB)
    float* pre = (float*)d_ws;

    k_pre_lds<<<64, 256, 0, stream>>>((const float4*)table, (float4*)pre);
    k_main<<<BB * NSTRIP, 256, 0, stream>>>((const float4*)x,
                                            (const float4*)table, w,
                                            (const float4*)bias,
                                            (const float4*)pre,
                                            (float4*)out);
}

// Round 13
// 31.015 us; speedup vs baseline: 1.2218x; 1.2218x over previous
//
#include <hip/hip_runtime.h>

// Problem constants (B,S,D,M) = (8, 2048, 1024, 128), R = 257
#define SS 2048
#define DDIM 1024
#define D4 256          // DDIM / 4 (float4 columns)
#define BB 8
#define STRIP 8
#define NSTRIP (SS / STRIP)   // 256

typedef float f32x4 __attribute__((ext_vector_type(4)));

__device__ __forceinline__ float4 f4zero() { return make_float4(0.f, 0.f, 0.f, 0.f); }
__device__ __forceinline__ float4 f4add(float4 a, float4 b) {
    return make_float4(a.x + b.x, a.y + b.y, a.z + b.z, a.w + b.w);
}
__device__ __forceinline__ float4 f4sub(float4 a, float4 b) {
    return make_float4(a.x - b.x, a.y - b.y, a.z - b.z, a.w - b.w);
}
__device__ __forceinline__ float4 f4mul(float4 a, float4 b) {
    return make_float4(a.x * b.x, a.y * b.y, a.z * b.z, a.w * b.w);
}
__device__ __forceinline__ float4 f4fma(float4 a, float4 b, float4 c) {
    return make_float4(fmaf(a.x, b.x, c.x), fmaf(a.y, b.y, c.y),
                       fmaf(a.z, b.z, c.z), fmaf(a.w, b.w, c.w));
}
__device__ __forceinline__ float4 f4fmas(float s, float4 b, float4 c) {
    return make_float4(fmaf(s, b.x, c.x), fmaf(s, b.y, c.y),
                       fmaf(s, b.z, c.z), fmaf(s, b.w, c.w));
}
__device__ __forceinline__ float4 f4scale(float4 a, float s) {
    return make_float4(a.x * s, a.y * s, a.z * s, a.w * s);
}
__device__ __forceinline__ float4 f4adds(float4 a, float s) {
    return make_float4(a.x + s, a.y + s, a.z + s, a.w + s);
}
__device__ __forceinline__ void nt_store(float4* p, float4 v) {
    __builtin_nontemporal_store(*(f32x4*)&v, (f32x4*)p);   // out never re-read (r11: win)
}
// NOTE: NT LOADS REVERTED — r12 measured +4.5 us: x halo reuse needs L2.

// ---------------------------------------------------------------------------
// k_pre_lds: ONE setup kernel. Pre[r][d] = sum_{r'=1..r} table[r'][d].
// 64 blocks x 256 threads; 4-row register chunks + 6-step Hillis-Steele LDS
// scan; max dependent-load chain = 4 (deep chains in setup cost 7-14 us:
// r5/r7 lessons).
// ---------------------------------------------------------------------------
__global__ __launch_bounds__(256) void k_pre_lds(const float4* __restrict__ tbl4,
                                                 float4* __restrict__ pre) {
    __shared__ float4 buf[2][64][4];    // 8 KB ping-pong
    const int t = threadIdx.x;
    const int k = t >> 2;               // chunk 0..63
    const int j = t & 3;                // col-within-block
    const int col = (blockIdx.x << 2) + j;   // 0..255

    const float4 p1 = tbl4[(4 * k + 1) * D4 + col];
    const float4 p2 = f4add(p1, tbl4[(4 * k + 2) * D4 + col]);
    const float4 p3 = f4add(p2, tbl4[(4 * k + 3) * D4 + col]);
    const float4 p4 = f4add(p3, tbl4[(4 * k + 4) * D4 + col]);

    buf[0][k][j] = p4;
    __syncthreads();
    int pb = 0;
#pragma unroll
    for (int s = 1; s < 64; s <<= 1) {
        float4 v = buf[pb][k][j];
        if (k >= s) v = f4add(v, buf[pb][k - s][j]);
        buf[pb ^ 1][k][j] = v;
        pb ^= 1;
        __syncthreads();
    }
    const float4 base = f4sub(buf[pb][k][j], p4);   // exclusive: rows 1..4k

    if (k == 0) pre[col] = f4zero();                 // Pre[0] = 0
    pre[(4 * k + 1) * D4 + col] = f4add(base, p1);
    pre[(4 * k + 2) * D4 + col] = f4add(base, p2);
    pre[(4 * k + 3) * D4 + col] = f4add(base, p3);
    if (k < 63) pre[(4 * k + 4) * D4 + col] = f4add(base, p4);  // row 256 unused
}

// ---------------------------------------------------------------------------
// k_main: out[b,i,d] = (w0*x[b,i-1] + (w1+S-1)*x[b,i] + w2*x[b,i+1] + pos(i,d)) / S
// Interior i in [128,1919]: pos = K0 + i*(T[2M]-T[0]), fully hoisted.
// Proven config: STRIP=8, plain __launch_bounds__(256), NT stores only.
// THIS ROUND: XCD-chunked swizzle — grid 2048 = 8 XCD x 256; orig =
// (bid&7)*256 + (bid>>3) puts batch k entirely on XCD k, so strips sharing
// halo rows share an L2 (halo: L3 round-trip -> L2 hit).
// ---------------------------------------------------------------------------
__global__ __launch_bounds__(256) void k_main(const float4* __restrict__ x4,
                                              const float4* __restrict__ tbl4,
                                              const float* __restrict__ w,
                                              const float4* __restrict__ bias4,
                                              const float4* __restrict__ pre4,
                                              float4* __restrict__ out4) {
    const int tid = threadIdx.x;          // d4
    // XCD-chunked bijective swizzle (2048 % 8 == 0)
    const int bid = ((blockIdx.x & 7) << 8) | (blockIdx.x >> 3);
    const int strip = bid & (NSTRIP - 1);
    const int b = bid >> 8;               // log2(256)
    const int i0 = strip * STRIP;

    // hoisted per-d constants (regular loads: L2-resident)
    const float4 T0  = tbl4[0 * D4 + tid];
    const float4 T2M = tbl4[256 * D4 + tid];
    const float4 Tm  = tbl4[128 * D4 + tid];
    const float4 Tmm = tbl4[127 * D4 + tid];
    const float4 Tmp = tbl4[129 * D4 + tid];
    const float4 bs  = bias4[tid];

    // w is (D,3) row-major; 3 float4s cover w for our 4 d's -> unscramble
    const float4* w4 = (const float4*)w;
    const float4 q0 = w4[3 * tid + 0];
    const float4 q1 = w4[3 * tid + 1];
    const float4 q2 = w4[3 * tid + 2];
    const float4 w0 = make_float4(q0.x, q0.w, q1.z, q2.y);
    const float4 w1 = make_float4(q0.y, q1.x, q1.w, q2.z);
    const float4 w2 = make_float4(q0.z, q1.y, q2.x, q2.w);
    const float4 w1s = f4adds(w1, (float)(SS - 1));
    const float invS = 1.0f / (float)SS;

    const float4* xr = x4 + (b * SS + i0) * D4 + tid;
    float4* orow = out4 + (b * SS + i0) * D4 + tid;

    if (strip >= 16 && strip <= 239) {
        // ------- interior path: i in [128, 1919] -------
        const float4 PF = pre4[255 * D4 + tid];
        float4 K0 = bs;
        K0 = f4fma(f4adds(w1, -1.f), Tm, K0);
        K0 = f4fma(w0, Tmm, K0);
        K0 = f4fma(w2, Tmp, K0);
        K0 = f4fmas(1920.f, T0, K0);
        K0 = f4fmas(-127.f, T2M, K0);
        K0 = f4add(K0, PF);
        const float4 Kc = f4sub(T2M, T0);
        // table constants dead from here -> small live set in the hot loop

        float4 xm = xr[-D4];        // i0-1 >= 127: safe
        float4 x0 = xr[0];
#pragma unroll
        for (int j = 0; j < STRIP; ++j) {
            const float4 xp = xr[(j + 1) * D4];   // i0+STRIP <= 1920: safe
            const float fi = (float)(i0 + j);
            float4 acc = f4fmas(fi, Kc, K0);
            acc = f4fma(w0, xm, acc);
            acc = f4fma(w1s, x0, acc);
            acc = f4fma(w2, xp, acc);
            nt_store(&orow[j * D4], f4scale(acc, invS));
            xm = x0; x0 = xp;
        }
    } else {
        // ------- edge path: general formula, per-i Pre lookups (L2-hot) -------
        float4 K0e = bs;
        K0e = f4fma(f4adds(w1, -1.f), Tm, K0e);
        const float4 w0Tmm = f4mul(w0, Tmm);
        const float4 w2Tmp = f4mul(w2, Tmp);

        float4 xm = (i0 == 0) ? f4zero() : xr[-D4];
        float4 x0 = xr[0];
#pragma unroll
        for (int j = 0; j < STRIP; ++j) {
            const int i = i0 + j;
            const float4 xp = (i < SS - 1) ? xr[(j + 1) * D4] : f4zero();
            const int cl = max(0, 1920 - i);          // clipped -M count (T[0])
            const int ch = max(0, i - 127);           // clipped +M count (T[2M])
            const int hi = min(i + 128, 255);
            const int lom1 = max(i - 1920, 0);        // lo - 1
            const float4 ph = pre4[hi * D4 + tid];
            const float4 pl = pre4[lom1 * D4 + tid];
            float4 pos = f4add(K0e, f4sub(ph, pl));
            pos = f4fmas((float)cl, T0, pos);
            pos = f4fmas((float)ch, T2M, pos);
            if (i >= 1)      pos = f4add(pos, w0Tmm);
            if (i <= SS - 2) pos = f4add(pos, w2Tmp);
            float4 acc = f4fma(w0, xm, pos);
            acc = f4fma(w1s, x0, acc);
            acc = f4fma(w2, xp, acc);
            nt_store(&orow[j * D4], f4scale(acc, invS));
            xm = x0; x0 = xp;
        }
    }
}

extern "C" void kernel_launch(void* const* d_in, const int* in_sizes, int n_in,
                              void* d_out, int out_size, void* d_ws, size_t ws_size,
                              hipStream_t stream) {
    const float* x     = (const float*)d_in[0];   // (B,S,D)
    const float* table = (const float*)d_in[1];   // (R,D) = (257,1024)
    const float* w     = (const float*)d_in[2];   // (D,3)
    const float* bias  = (const float*)d_in[3];   // (D,)
    float* out = (float*)d_out;

    // ws layout: Pre[256][1024] floats (1 MiB)
    float* pre = (float*)d_ws;

    k_pre_lds<<<64, 256, 0, stream>>>((const float4*)table, (float4*)pre);
    k_main<<<BB * NSTRIP, 256, 0, stream>>>((const float4*)x,
                                            (const float4*)table, w,
                                            (const float4*)bias,
                                            (const float4*)pre,
                                            (float4*)out);
}